// Round 3
// baseline (96.608 us; speedup 1.0000x reference)
//
#include <hip/hip_runtime.h>
#include <hip/hip_bf16.h>

// Problem constants (match reference)
#define CIN_  128
#define H_    28
#define W_    28
#define COUT_ 32
#define B_    512
// GEMM view per (b,h): Y[32 x 28] = Wm[32 x 384] * Xwin[384 x 28]
// K order: kappa = tap*128 + channel, chunked in 12 chunks of 32.

typedef __attribute__((ext_vector_type(8))) short short8;  // 8 bf16 in 4 VGPRs
typedef __attribute__((ext_vector_type(4))) float f32x4;

__device__ __forceinline__ short f2bf(float f) {
    __hip_bfloat16 h = __float2bfloat16(f);    // RNE, single HW cvt
    union { __hip_bfloat16 h; short s; } u; u.h = h;
    return u.s;
}

// ---------------------------------------------------------------------------
// Pre-pass: build bf16 A-fragments of Wm in d_ws.
// Fragment f = mt*12 + kc  (mt: 0..1 M-tile of 16 couts, kc: 0..11 K-chunk of 32)
// Element (lane l, slot j): Wm[jo = mt*16 + (l&15)][i = (kc&3)*32 + (l>>4)*8 + j][tap = kc>>2]
// Stored flat: ws[f*512 + l*8 + j]  -> lane l loads 16B at f*1024 + l*16 bytes.
// ---------------------------------------------------------------------------
__global__ void prep_w_kernel(const float* __restrict__ w, short* __restrict__ wsA) {
    int t = blockIdx.x * 256 + threadIdx.x;      // 24*512 = 12288 threads
    int frag = t >> 9;
    int rem  = t & 511;
    int l = rem >> 3;
    int j = rem & 7;
    int mt = frag / 12;
    int kc = frag % 12;
    int tap = kc >> 2;
    int i  = (kc & 3) * 32 + (l >> 4) * 8 + j;
    int jo = mt * 16 + (l & 15);
    wsA[t] = f2bf(w[(jo * CIN_ + i) * 3 + tap]);
}

// ---------------------------------------------------------------------------
// Main kernel v3: grid (28, 512), ONE wave per block (64 threads), one h-row
// per wave. No __syncthreads anywhere: the LDS buffer is wave-private, so a
// single s_waitcnt lgkmcnt(0) orders staging ds_writes before GEMM ds_reads.
// LDS: x-row transposed [wt 0..29][128 ch] bf16, XOR-swizzled:
//   (wt, i) at short index  wt*128 + (((i>>3) ^ (wt&15))<<3 | (i&7))
// wt = w + tap (w_real = wt-1). Rows 0 and 29 zeroed (padding). B-reads with
// wt in 30..33 only feed discarded output cols (wcol >= 28); their LDS row is
// clamped to 29 so the access stays in-bounds.
// ---------------------------------------------------------------------------
template<bool USE_WS>
__global__ __launch_bounds__(64, 5)
void conv_kernel(const float* __restrict__ x, const float* __restrict__ w,
                 const short* __restrict__ wsA, float* __restrict__ out) {
    __shared__ short wbuf[30 * CIN_];            // 7680 B
    const int l = threadIdx.x;                   // 0..63
    const int h = blockIdx.x;                    // 0..27
    const int b = blockIdx.y;                    // 0..511

    const float* xb = x + (size_t)b * (CIN_ * H_ * W_);

    // ---- zero pad rows wt=0 and wt=29 (wave-private, 1 b32 per lane each) --
    *reinterpret_cast<int*>(&wbuf[0 * CIN_ + l * 2])  = 0;
    *reinterpret_cast<int*>(&wbuf[29 * CIN_ + l * 2]) = 0;

    // ---- A fragments, first K-half (kc 0..5), issued early (L1/L2-hot) ----
    short8 a0[6], a1[6];
    if (USE_WS) {
#pragma unroll
        for (int k6 = 0; k6 < 6; ++k6) {
            a0[k6] = *reinterpret_cast<const short8*>(wsA + k6 * 512 + l * 8);
            a1[k6] = *reinterpret_cast<const short8*>(wsA + (12 + k6) * 512 + l * 8);
        }
    } else {
#pragma unroll
        for (int k6 = 0; k6 < 6; ++k6) {
            int tap = k6 >> 2;
            int ib  = (k6 & 3) * 32 + (l >> 4) * 8;
#pragma unroll
            for (int j = 0; j < 8; ++j) {
                a0[k6][j] = f2bf(w[((l & 15) * CIN_ + ib + j) * 3 + tap]);
                a1[k6][j] = f2bf(w[((16 + (l & 15)) * CIN_ + ib + j) * 3 + tap]);
            }
        }
    }

    // ---- stage x[b,:,h,:] -> LDS, two batches of 7 f32x4 loads ----
#pragma unroll
    for (int half = 0; half < 2; ++half) {
        f32x4 vb[7];
#pragma unroll
        for (int it = 0; it < 7; ++it) {
            int f4 = (half * 7 + it) * 64 + l;   // 0..895
            int i  = f4 / 7;                     // channel
            int w4 = f4 % 7;                     // quad index in row
            vb[it] = *reinterpret_cast<const f32x4*>(xb + i * (H_ * W_) + h * W_ + w4 * 4);
        }
#pragma unroll
        for (int it = 0; it < 7; ++it) {
            int f4 = (half * 7 + it) * 64 + l;
            int i  = f4 / 7;
            int w4 = f4 % 7;
#pragma unroll
            for (int e = 0; e < 4; ++e) {
                int wt   = w4 * 4 + e + 1;       // 1..28
                int sidx = wt * CIN_ + ((((i >> 3) ^ (wt & 15)) << 3) | (i & 7));
                wbuf[sidx] = f2bf(vb[it][e]);
            }
        }
    }

    // ---- order wave-private ds_writes before ds_reads (no barrier needed) --
    asm volatile("s_waitcnt lgkmcnt(0)" ::: "memory");
    __builtin_amdgcn_sched_barrier(0);

    // ---- GEMM: 2 M-tiles x 2 N-tiles x 12 K-chunks of 32 ----
    f32x4 acc[2][2];
#pragma unroll
    for (int mt = 0; mt < 2; ++mt)
#pragma unroll
        for (int nt = 0; nt < 2; ++nt)
#pragma unroll
            for (int q = 0; q < 4; ++q) acc[mt][nt][q] = 0.0f;

#pragma unroll
    for (int half = 0; half < 2; ++half) {
        if (half == 1) {                         // reload A frags, second K-half
            if (USE_WS) {
#pragma unroll
                for (int k6 = 0; k6 < 6; ++k6) {
                    int kc = 6 + k6;
                    a0[k6] = *reinterpret_cast<const short8*>(wsA + kc * 512 + l * 8);
                    a1[k6] = *reinterpret_cast<const short8*>(wsA + (12 + kc) * 512 + l * 8);
                }
            } else {
#pragma unroll
                for (int k6 = 0; k6 < 6; ++k6) {
                    int kc  = 6 + k6;
                    int tap = kc >> 2;
                    int ib  = (kc & 3) * 32 + (l >> 4) * 8;
#pragma unroll
                    for (int j = 0; j < 8; ++j) {
                        a0[k6][j] = f2bf(w[((l & 15) * CIN_ + ib + j) * 3 + tap]);
                        a1[k6][j] = f2bf(w[((16 + (l & 15)) * CIN_ + ib + j) * 3 + tap]);
                    }
                }
            }
        }
#pragma unroll
        for (int k6 = 0; k6 < 6; ++k6) {
            int kc  = half * 6 + k6;
            int tap = kc >> 2;
            int c   = (kc & 3) * 4 + (l >> 4);   // chunk index of lane's 8 channels
#pragma unroll
            for (int nt = 0; nt < 2; ++nt) {
                int wt  = nt * 16 + (l & 15) + tap;     // 0..33
                int wtc = wt > 29 ? 29 : wt;            // clamp: rows >29 feed dead cols
                const short8 bfrag = *reinterpret_cast<const short8*>(
                    &wbuf[wtc * CIN_ + ((c ^ (wtc & 15)) << 3)]);
                acc[0][nt] = __builtin_amdgcn_mfma_f32_16x16x32_bf16(
                    a0[k6], bfrag, acc[0][nt], 0, 0, 0);
                acc[1][nt] = __builtin_amdgcn_mfma_f32_16x16x32_bf16(
                    a1[k6], bfrag, acc[1][nt], 0, 0, 0);
            }
        }
    }

    // ---- store with roll: y row h -> out row (h+1)%28 ----
    float* ob = out + (size_t)b * (COUT_ * H_ * W_);
    const int ho = (h + 1 == H_) ? 0 : (h + 1);
#pragma unroll
    for (int mt = 0; mt < 2; ++mt)
#pragma unroll
        for (int nt = 0; nt < 2; ++nt)
#pragma unroll
            for (int rr = 0; rr < 4; ++rr) {
                int j    = mt * 16 + (l >> 4) * 4 + rr;
                int wcol = nt * 16 + (l & 15);
                if (wcol < W_)
                    ob[(j * H_ + ho) * W_ + wcol] = acc[mt][nt][rr];
            }
}

extern "C" void kernel_launch(void* const* d_in, const int* in_sizes, int n_in,
                              void* d_out, int out_size, void* d_ws, size_t ws_size,
                              hipStream_t stream) {
    (void)in_sizes; (void)n_in; (void)out_size;
    const float* x = (const float*)d_in[0];
    const float* w = (const float*)d_in[1];
    float* out = (float*)d_out;

    if (ws_size >= (size_t)(24 * 512 * sizeof(short))) {
        short* wsA = (short*)d_ws;
        prep_w_kernel<<<dim3(48), dim3(256), 0, stream>>>(w, wsA);
        conv_kernel<true><<<dim3(28, 512), dim3(64), 0, stream>>>(x, w, wsA, out);
    } else {
        conv_kernel<false><<<dim3(28, 512), dim3(64), 0, stream>>>(x, w, (const short*)nullptr, out);
    }
}

// Round 4
// 58.691 us; speedup vs baseline: 1.6460x; 1.6460x over previous
//
#include <hip/hip_runtime.h>
#include <hip/hip_bf16.h>

// Problem constants (match reference)
#define CIN_  128
#define H_    28
#define W_    28
#define COUT_ 32
#define B_    512
// GEMM view per (b,h): Y[32 x 28] = Wm[32 x 384] * Xwin[384 x 28]
// K order: kappa = tap*128 + channel, chunked in 12 chunks of 32.

typedef __attribute__((ext_vector_type(8))) short short8;  // 8 bf16 in 4 VGPRs
typedef __attribute__((ext_vector_type(4))) float f32x4;

__device__ __forceinline__ short f2bf(float f) {
    __hip_bfloat16 h = __float2bfloat16(f);    // RNE, single HW cvt
    union { __hip_bfloat16 h; short s; } u; u.h = h;
    return u.s;
}

// ---------------------------------------------------------------------------
// Pre-pass: build bf16 A-fragments of Wm in d_ws.
// Fragment f = mt*12 + kc  (mt: 0..1 M-tile of 16 couts, kc: 0..11 K-chunk of 32)
// Element (lane l, slot j): Wm[jo = mt*16 + (l&15)][i = (kc&3)*32 + (l>>4)*8 + j][tap = kc>>2]
// Stored flat: ws[f*512 + l*8 + j]  -> lane l loads 16B at f*1024 + l*16 bytes.
// ---------------------------------------------------------------------------
__global__ void prep_w_kernel(const float* __restrict__ w, short* __restrict__ wsA) {
    int t = blockIdx.x * 256 + threadIdx.x;      // 24*512 = 12288 threads
    int frag = t >> 9;
    int rem  = t & 511;
    int l = rem >> 3;
    int j = rem & 7;
    int mt = frag / 12;
    int kc = frag % 12;
    int tap = kc >> 2;
    int i  = (kc & 3) * 32 + (l >> 4) * 8 + j;
    int jo = mt * 16 + (l & 15);
    wsA[t] = f2bf(w[(jo * CIN_ + i) * 3 + tap]);
}

// ---------------------------------------------------------------------------
// Main kernel v4: grid (7, 512), block 256 (4 waves). Wave wv computes row
// h = blockIdx.x*4 + wv. Block-cooperative staging of 4 consecutive rows:
// per channel i, x[b, i, h0:h0+4, :] is one contiguous 448-B segment, read as
// 28 f32x4 quads (q = 0..27 -> hl = q/7, w4 = q%7). One barrier, then each
// wave runs its own 32x28x384 GEMM from its private LDS buffer.
// LDS per wave: x-row transposed [wt 0..29][128 ch] bf16, XOR-swizzled:
//   (wt, i) at short index  wt*128 + (((i>>3) ^ (wt&15))<<3 | (i&7))
// wt = w + tap (w_real = wt-1). Rows 0 and 29 zeroed (padding). B-reads with
// wt in 30..33 only feed discarded output cols (wcol >= 28); clamp to 29.
// ---------------------------------------------------------------------------
template<bool USE_WS>
__global__ __launch_bounds__(256, 5)
void conv_kernel(const float* __restrict__ x, const float* __restrict__ w,
                 const short* __restrict__ wsA, float* __restrict__ out) {
    __shared__ short lds[4][30 * CIN_];          // 4 x 7680 B = 30720 B
    const int tid = threadIdx.x;
    const int wv  = tid >> 6;
    const int l   = tid & 63;
    const int hg  = blockIdx.x;                  // 0..6
    const int b   = blockIdx.y;                  // 0..511
    const int h0  = hg * 4;

    const float* xb = x + (size_t)b * (CIN_ * H_ * W_);

    // ---- zero pad rows wt=0 and wt=29 in this wave's buffer ----
    // 64 threads per buffer, 4 shorts (8 B) each: 256 shorts = rows 0 + 29.
    {
        int s   = (tid & 63) * 4;                // 0..252
        int row = (s >= 128) ? 29 : 0;
        int c   = s & 127;
        *reinterpret_cast<ulong1*>(&lds[wv][row * CIN_ + c]) = ulong1{0};
    }

    // ---- block-cooperative staging: 128 ch x 28 quads (4 rows x 7) ----
#pragma unroll
    for (int half = 0; half < 2; ++half) {
        f32x4 vb[7];
#pragma unroll
        for (int it = 0; it < 7; ++it) {
            int f4 = (half * 7 + it) * 256 + tid;    // 0..3583
            int i  = f4 / 28;                        // channel
            int q  = f4 % 28;                        // quad within 448-B segment
            vb[it] = *reinterpret_cast<const f32x4*>(xb + i * (H_ * W_) + h0 * W_ + q * 4);
        }
#pragma unroll
        for (int it = 0; it < 7; ++it) {
            int f4 = (half * 7 + it) * 256 + tid;
            int i  = f4 / 28;
            int q  = f4 % 28;
            int hl = q / 7;                          // local row 0..3
            int w4 = q % 7;
            short* buf = lds[hl];
#pragma unroll
            for (int e = 0; e < 4; ++e) {
                int wt   = w4 * 4 + e + 1;           // 1..28
                int sidx = wt * CIN_ + ((((i >> 3) ^ (wt & 15)) << 3) | (i & 7));
                buf[sidx] = f2bf(vb[it][e]);
            }
        }
    }
    __syncthreads();

    // ---- per-wave GEMM: 2 M-tiles x 2 N-tiles x 12 K-chunks of 32 ----
    short* wbuf = lds[wv];
    const int h = h0 + wv;

    f32x4 acc[2][2];
#pragma unroll
    for (int mt = 0; mt < 2; ++mt)
#pragma unroll
        for (int nt = 0; nt < 2; ++nt)
#pragma unroll
            for (int q = 0; q < 4; ++q) acc[mt][nt][q] = 0.0f;

#pragma unroll
    for (int half = 0; half < 2; ++half) {
        short8 a0[6], a1[6];                     // 12 frags live = 48 VGPR
        if (USE_WS) {
#pragma unroll
            for (int k6 = 0; k6 < 6; ++k6) {
                int kc = half * 6 + k6;
                a0[k6] = *reinterpret_cast<const short8*>(wsA + kc * 512 + l * 8);
                a1[k6] = *reinterpret_cast<const short8*>(wsA + (12 + kc) * 512 + l * 8);
            }
        } else {
#pragma unroll
            for (int k6 = 0; k6 < 6; ++k6) {
                int kc  = half * 6 + k6;
                int tap = kc >> 2;
                int ib  = (kc & 3) * 32 + (l >> 4) * 8;
#pragma unroll
                for (int j = 0; j < 8; ++j) {
                    a0[k6][j] = f2bf(w[((l & 15) * CIN_ + ib + j) * 3 + tap]);
                    a1[k6][j] = f2bf(w[((16 + (l & 15)) * CIN_ + ib + j) * 3 + tap]);
                }
            }
        }
#pragma unroll
        for (int k6 = 0; k6 < 6; ++k6) {
            int kc  = half * 6 + k6;
            int tap = kc >> 2;
            int c   = (kc & 3) * 4 + (l >> 4);   // chunk index of lane's 8 channels
#pragma unroll
            for (int nt = 0; nt < 2; ++nt) {
                int wt  = nt * 16 + (l & 15) + tap;     // 0..33
                int wtc = wt > 29 ? 29 : wt;            // clamp: rows >29 feed dead cols
                const short8 bfrag = *reinterpret_cast<const short8*>(
                    &wbuf[wtc * CIN_ + ((c ^ (wtc & 15)) << 3)]);
                acc[0][nt] = __builtin_amdgcn_mfma_f32_16x16x32_bf16(
                    a0[k6], bfrag, acc[0][nt], 0, 0, 0);
                acc[1][nt] = __builtin_amdgcn_mfma_f32_16x16x32_bf16(
                    a1[k6], bfrag, acc[1][nt], 0, 0, 0);
            }
        }
    }

    // ---- store with roll: y row h -> out row (h+1)%28 ----
    float* ob = out + (size_t)b * (COUT_ * H_ * W_);
    const int ho = (h + 1 == H_) ? 0 : (h + 1);
#pragma unroll
    for (int mt = 0; mt < 2; ++mt)
#pragma unroll
        for (int nt = 0; nt < 2; ++nt)
#pragma unroll
            for (int rr = 0; rr < 4; ++rr) {
                int j    = mt * 16 + (l >> 4) * 4 + rr;
                int wcol = nt * 16 + (l & 15);
                if (wcol < W_)
                    ob[(j * H_ + ho) * W_ + wcol] = acc[mt][nt][rr];
            }
}

extern "C" void kernel_launch(void* const* d_in, const int* in_sizes, int n_in,
                              void* d_out, int out_size, void* d_ws, size_t ws_size,
                              hipStream_t stream) {
    (void)in_sizes; (void)n_in; (void)out_size;
    const float* x = (const float*)d_in[0];
    const float* w = (const float*)d_in[1];
    float* out = (float*)d_out;

    if (ws_size >= (size_t)(24 * 512 * sizeof(short))) {
        short* wsA = (short*)d_ws;
        prep_w_kernel<<<dim3(48), dim3(256), 0, stream>>>(w, wsA);
        conv_kernel<true><<<dim3(7, 512), dim3(256), 0, stream>>>(x, w, wsA, out);
    } else {
        conv_kernel<false><<<dim3(7, 512), dim3(256), 0, stream>>>(x, w, (const short*)nullptr, out);
    }
}